// Round 6
// baseline (50.405 us; speedup 1.0000x reference)
//
#include <hip/hip_runtime.h>
#include <math.h>

// Chamfer distance, B=8, N=M=4096, D=3, fp32.
//
// R6 = DIAGNOSTIC round. R1/R3/R4/R5 all landed at 30.5-31.0 us despite 2x
// VALU, 4x LDS, 2x occupancy changes -> wall time is pipe-insensitive.
// Hypotheses: H1 harness ~30us floor (main <=15us, invisible); H2 main is
// really ~25us latency-bound. Discriminator: run the SAME R5 kernel with a
// 2x-duplicated grid (bid and bid+1024 compute identical partials; final
// kernel halves the scale). H1 -> dur unchanged ~31. H2 -> dur ~55, and
// chamfer_main (now ~50us) finally beats the 39us harness fills into the
// rocprof top-5 so we get VALUBusy/Occupancy for the real kernel.

typedef float f32x2 __attribute__((ext_vector_type(2)));

#define NPTS 4096
#define BATCH 8
#define CPAIRS 1024                  // b-point pairs per LDS chunk (2048 pts)
#define NCHUNK 2
#define PA 16                        // a-points per thread
#define APB 64                       // a-points per block (4 waves * 16)
#define NWORK 1024                   // distinct work items
#define DUP 2                        // grid duplication factor (diagnostic)
#define NBLOCKS (NWORK * DUP)        // 2048
#define RSTRIDE 68                   // tail-transpose row stride (floats)

// d = c.lo * q + acc  (c.lo broadcast to both halves)
__device__ __forceinline__ f32x2 pk_fma_lo(f32x2 c, f32x2 q, f32x2 acc) {
    f32x2 d;
    asm("v_pk_fma_f32 %0, %1, %2, %3 op_sel:[0,0,0] op_sel_hi:[0,1,1]"
        : "=v"(d) : "v"(c), "v"(q), "v"(acc));
    return d;
}
// d = c.hi * q + acc  (c.hi broadcast to both halves)
__device__ __forceinline__ f32x2 pk_fma_hi(f32x2 c, f32x2 q, f32x2 acc) {
    f32x2 d;
    asm("v_pk_fma_f32 %0, %1, %2, %3 op_sel:[1,0,0] op_sel_hi:[1,1,1]"
        : "=v"(d) : "v"(c), "v"(q), "v"(acc));
    return d;
}
__device__ __forceinline__ void vmin3(float& acc, float a, float b) {
    asm("v_min3_f32 %0, %1, %2, %3" : "=v"(acc) : "v"(acc), "v"(a), "v"(b));
}

__global__ __launch_bounds__(256, 4) void chamfer_main(
    const float* __restrict__ pcs1, const float* __restrict__ pcs2,
    float* __restrict__ partials)
{
    __shared__ float4 lds[2 * CPAIRS];        // 32 KB; reused by tail reduce
    float4* bx = lds;                         // (x0,x1,y0,y1) per pair
    float4* bz = lds + CPAIRS;                // (z0,z1,w0,w1) per pair

    const int bid  = blockIdx.x;
    const int bid2 = bid & (NWORK - 1);       // duplicate work item
    const int dir  = bid2 >> 9;
    const int b    = (bid2 >> 6) & 7;
    const int ach  = bid2 & 63;

    const float* A  = dir ? pcs2 : pcs1;
    const float* Bp = dir ? pcs1 : pcs2;
    const float* abase = A  + (size_t)b * NPTS * 3;
    const float* bbase = Bp + (size_t)b * NPTS * 3;

    const int tid = threadIdx.x;
    const int w   = tid >> 6;
    const int l   = tid & 63;

    // ---- a-point coefficients: 2 a-points packed per f32x2 ----
    const int apt = ach * APB + w * PA;
    f32x2 cx[PA / 2], cy[PA / 2], cz[PA / 2];
    float tmin[PA];
#pragma unroll
    for (int p2 = 0; p2 < PA / 2; ++p2) {
        const float* s = abase + (size_t)(apt + 2 * p2) * 3;
        cx[p2] = (f32x2){-2.0f * s[0], -2.0f * s[3]};
        cy[p2] = (f32x2){-2.0f * s[1], -2.0f * s[4]};
        cz[p2] = (f32x2){-2.0f * s[2], -2.0f * s[5]};
        tmin[2 * p2]     = 3.4e38f;
        tmin[2 * p2 + 1] = 3.4e38f;
    }

    // ---- chunked sweep over the b-cloud ----
    for (int c = 0; c < NCHUNK; ++c) {
        if (c) __syncthreads();               // prev compute done
#pragma unroll
        for (int i = 0; i < CPAIRS / 256; ++i) {   // stage 1024 pairs
            int j  = i * 256 + tid;
            int gp = c * CPAIRS + j;
            const float* s = bbase + (size_t)gp * 6;
            float x0 = s[0], y0 = s[1], z0 = s[2];
            float x1 = s[3], y1 = s[4], z1 = s[5];
            bx[j] = make_float4(x0, x1, y0, y1);
            bz[j] = make_float4(z0, z1,
                                fmaf(x0, x0, fmaf(y0, y0, z0 * z0)),
                                fmaf(x1, x1, fmaf(y1, y1, z1 * z1)));
        }
        __syncthreads();

        // 16 t-steps; lane l reads pair t*64+l (stride-1, conflict-free)
#pragma unroll 4
        for (int t = 0; t < CPAIRS / 64; ++t) {
            float4 X = bx[t * 64 + l];
            float4 Z = bz[t * 64 + l];
            f32x2 qx = (f32x2){X.x, X.y};
            f32x2 qy = (f32x2){X.z, X.w};
            f32x2 qz = (f32x2){Z.x, Z.y};
            f32x2 qw = (f32x2){Z.z, Z.w};
#pragma unroll
            for (int p2 = 0; p2 < PA / 2; ++p2) {
                f32x2 d0 = pk_fma_lo(cz[p2], qz, qw);
                d0 = pk_fma_lo(cy[p2], qy, d0);
                d0 = pk_fma_lo(cx[p2], qx, d0);
                vmin3(tmin[2 * p2], d0.x, d0.y);
                f32x2 d1 = pk_fma_hi(cz[p2], qz, qw);
                d1 = pk_fma_hi(cy[p2], qy, d1);
                d1 = pk_fma_hi(cx[p2], qx, d1);
                vmin3(tmin[2 * p2 + 1], d1.x, d1.y);
            }
        }
    }

    // ---- cross-lane min: transpose into LDS, single-wave pass ----
    __syncthreads();                          // done with bx/bz
    float* lds2 = (float*)lds;                // 64 x 68 floats = 17.4 KB
#pragma unroll
    for (int p = 0; p < PA; ++p)
        lds2[(w * PA + p) * RSTRIDE + l] = tmin[p];
    __syncthreads();

    if (tid < 64) {
        const int g = tid;                    // block-local a-point
        float m = 3.4e38f;
        const float4* row = (const float4*)&lds2[g * RSTRIDE];
#pragma unroll
        for (int i = 0; i < 16; ++i) {
            float4 v = row[i];
            m = fminf(fminf(m, fminf(v.x, v.y)), fminf(v.z, v.w));
        }
        const int ap = ach * APB + g;
        float x = abase[ap * 3 + 0];
        float y = abase[ap * 3 + 1];
        float z = abase[ap * 3 + 2];
        float sq = fmaf(x, x, fmaf(y, y, z * z));
        float s = sqrtf(fmaxf(sq + m, 0.0f));  // clamp cancellation
#pragma unroll
        for (int off = 1; off < 64; off <<= 1)
            s += __shfl_xor(s, off, 64);
        if (g == 0) partials[bid] = s;
    }
}

__global__ __launch_bounds__(256) void chamfer_final(
    const float* __restrict__ partials, int n, float scale,
    float* __restrict__ out)
{
    __shared__ float ws[4];
    const int t = threadIdx.x;
    float v = 0.0f;
    for (int i = t; i < n; i += 256) v += partials[i];
#pragma unroll
    for (int off = 1; off < 64; off <<= 1) v += __shfl_xor(v, off, 64);
    if ((t & 63) == 0) ws[t >> 6] = v;
    __syncthreads();
    if (t == 0)
        out[0] = (ws[0] + ws[1] + ws[2] + ws[3]) * scale;
}

extern "C" void kernel_launch(void* const* d_in, const int* in_sizes, int n_in,
                              void* d_out, int out_size, void* d_ws, size_t ws_size,
                              hipStream_t stream) {
    const float* pcs1 = (const float*)d_in[0];
    const float* pcs2 = (const float*)d_in[1];
    float* out      = (float*)d_out;
    float* partials = (float*)d_ws;   // NBLOCKS floats = 8 KB scratch

    chamfer_main <<<dim3(NBLOCKS), dim3(256), 0, stream>>>(pcs1, pcs2, partials);
    // each work item counted DUP times -> scale by 1/(DUP * 65536)
    chamfer_final<<<dim3(1), dim3(256), 0, stream>>>(
        partials, NBLOCKS, 1.0f / (65536.0f * DUP), out);
}

// Round 7
// 25.418 us; speedup vs baseline: 1.9830x; 1.9830x over previous
//
#include <hip/hip_runtime.h>
#include <math.h>

// Chamfer distance, B=8, N=M=4096, D=3, fp32.
// R7: split-bf16 MFMA. D[r][c] = sqA[r] - 2 a_r . b_c via
// v_mfma_f32_32x32x16_bf16 with K packed as
//   A_k = [h0,h1,h2, h0,h1,h2, l0,l1 | l2, l0,l1,l2, shi,slo, 0,0]
//   B_k = [bh0,bh1,bh2, bl0,bl1,bl2, bh0,bh1 | bh2, bl0,bl1,bl2, 1,1, 0,0]
// where h/l = hi/lo bf16 split of (-2a), bh/bl of raw b, shi/slo of |a|^2.
// Sum over k = (-2a).(b) to ~2^-17 rel + |a|^2 -> fp32-grade d values.
// Per direction: col = B-role point (C/D layout col=lane&31, verified m74),
// min over rows is LANE-LOCAL (16 acc regs) -> ~8 v_min3 per 1024 pairs.
// dist_X = colmin + |x|^2 (fp32, added once at end), clamp, sqrt, mean.

typedef __attribute__((ext_vector_type(8)))  short bf16x8;
typedef __attribute__((ext_vector_type(16))) float f32x16;
typedef float f32x2 __attribute__((ext_vector_type(2)));

#define NPTS 4096
#define BATCH 8
#define FRAG_PER_B 8192u   // 128 tiles * 2 halves * 32 rows (uint4 each)

union FragCast { uint4 u; bf16x8 v; };

__device__ __forceinline__ unsigned short f2bf(float f) {
    unsigned u = __float_as_uint(f);
    return (unsigned short)((u + 0x7FFFu + ((u >> 16) & 1u)) >> 16);
}
__device__ __forceinline__ float bf2f(unsigned short h) {
    return __uint_as_float(((unsigned)h) << 16);
}
__device__ __forceinline__ unsigned pk(unsigned short a, unsigned short b) {
    return (unsigned)a | ((unsigned)b << 16);
}

// ---------------- prep: build MFMA fragments in d_ws ----------------
__global__ __launch_bounds__(256) void chamfer_prep(
    const float* __restrict__ pcs1, const float* __restrict__ pcs2,
    uint4* __restrict__ fa1, uint4* __restrict__ fa2,
    uint4* __restrict__ fb1, uint4* __restrict__ fb2,
    float* __restrict__ sqarr)
{
    const int gid   = blockIdx.x * 256 + threadIdx.x;  // [0, 65536)
    const int cloud = gid >> 15;
    const int idx   = gid & 32767;
    const int b     = idx >> 12;
    const int pt    = idx & 4095;

    const float* src = (cloud ? pcs2 : pcs1) + ((size_t)b * NPTS + pt) * 3;
    float x = src[0], y = src[1], z = src[2];
    float sq = fmaf(x, x, fmaf(y, y, z * z));

    // A-role: hi/lo split of -2*coord, plus split of |a|^2
    float m2x = -2.0f * x, m2y = -2.0f * y, m2z = -2.0f * z;
    unsigned short hx = f2bf(m2x), hy = f2bf(m2y), hz = f2bf(m2z);
    unsigned short lx = f2bf(m2x - bf2f(hx));
    unsigned short ly = f2bf(m2y - bf2f(hy));
    unsigned short lz = f2bf(m2z - bf2f(hz));
    unsigned short sh = f2bf(sq);
    unsigned short sl = f2bf(sq - bf2f(sh));

    // B-role: hi/lo split of raw coord
    unsigned short px = f2bf(x), py = f2bf(y), pz = f2bf(z);
    unsigned short qx = f2bf(x - bf2f(px));
    unsigned short qy = f2bf(y - bf2f(py));
    unsigned short qz = f2bf(z - bf2f(pz));
    const unsigned short ONE = 0x3F80;

    uint4 a0 = make_uint4(pk(hx, hy), pk(hz, hx), pk(hy, hz), pk(lx, ly));
    uint4 a1 = make_uint4(pk(lz, lx), pk(ly, lz), pk(sh, sl), 0u);
    uint4 b0 = make_uint4(pk(px, py), pk(pz, qx), pk(qy, qz), pk(px, py));
    uint4 b1 = make_uint4(pk(pz, qx), pk(qy, qz), pk(ONE, ONE), 0u);

    const int tile = pt >> 5, row = pt & 31;
    const size_t i0 = (size_t)b * FRAG_PER_B + ((size_t)tile * 2 + 0) * 32 + row;
    const size_t i1 = (size_t)b * FRAG_PER_B + ((size_t)tile * 2 + 1) * 32 + row;
    uint4* fa = cloud ? fa2 : fa1;
    uint4* fb = cloud ? fb2 : fb1;
    fa[i0] = a0; fa[i1] = a1;
    fb[i0] = b0; fb[i1] = b1;
    sqarr[((size_t)cloud * 8 + b) * NPTS + pt] = sq;
}

// ---------------- main: 512 blocks x 256 threads (4 waves) ----------------
// dir = bid>>8 (0: dists for pcs1), b = (bid>>5)&7, mchunk = bid&31.
// wave w owns m-tile mchunk*4+w (32 cols); sweeps 128 n-tiles, A-frags
// LDS-staged in 4 phases of 32 tiles (32 KB).
__global__ __launch_bounds__(256, 2) void chamfer_mfma(
    const uint4* __restrict__ fa1, const uint4* __restrict__ fa2,
    const uint4* __restrict__ fb1, const uint4* __restrict__ fb2,
    const float* __restrict__ sqarr, float* __restrict__ partials)
{
    __shared__ uint4 stage[2048];   // 32 tiles * 2 halves * 32 rows

    const int bid = blockIdx.x;
    const int dir = bid >> 8;
    const int b   = (bid >> 5) & 7;
    const int mch = bid & 31;

    const uint4* fA = (dir ? fa1 : fa2) + (size_t)b * FRAG_PER_B;  // A-role: other cloud
    const uint4* fB = (dir ? fb2 : fb1) + (size_t)b * FRAG_PER_B;  // B-role: this dir's cloud
    const float* sqB = sqarr + ((size_t)dir * 8 + b) * NPTS;

    const int tid = threadIdx.x;
    const int w   = tid >> 6;
    const int l   = tid & 63;
    const int hf  = l >> 5;
    const int ln  = l & 31;
    const int mtile = mch * 4 + w;

    FragCast bq;
    bq.u = fB[((size_t)mtile * 2 + hf) * 32 + ln];

    const f32x16 cz = {0.f,0.f,0.f,0.f,0.f,0.f,0.f,0.f,
                       0.f,0.f,0.f,0.f,0.f,0.f,0.f,0.f};
    float acc0 = 3.4e38f, acc1 = 3.4e38f;

    for (int phase = 0; phase < 4; ++phase) {
        __syncthreads();                      // prev phase's reads done
#pragma unroll
        for (int i = 0; i < 8; ++i)
            stage[i * 256 + tid] = fA[(size_t)phase * 2048 + i * 256 + tid];
        __syncthreads();

#pragma unroll 4
        for (int j = 0; j < 32; ++j) {
            FragCast aq;
            aq.u = stage[(j * 2 + hf) * 32 + ln];
            f32x16 D = __builtin_amdgcn_mfma_f32_32x32x16_bf16(
                aq.v, bq.v, cz, 0, 0, 0);
            float m0 = fminf(fminf(D[0],  D[1]),  D[2]);
            float m1 = fminf(fminf(D[3],  D[4]),  D[5]);
            float m2 = fminf(fminf(D[6],  D[7]),  D[8]);
            float m3 = fminf(fminf(D[9],  D[10]), D[11]);
            float m4 = fminf(fminf(D[12], D[13]), D[14]);
            float m5 = fminf(fminf(m0, m1), D[15]);
            float m6 = fminf(fminf(m2, m3), m4);
            if (j & 1) acc1 = fminf(acc1, fminf(m5, m6));
            else       acc0 = fminf(acc0, fminf(m5, m6));
        }
    }

    // combine halves (lane l <-> l+32 hold complementary row sets, same col)
    float accmin = fminf(acc0, acc1);
    accmin = fminf(accmin, __shfl_xor(accmin, 32, 64));

    const int col = mtile * 32 + ln;
    float s = 0.0f;
    if (l < 32) {
        float d = fmaxf(accmin + sqB[col], 0.0f);  // clamp cancellation
        s = sqrtf(d);
    }
#pragma unroll
    for (int off = 1; off < 64; off <<= 1)
        s += __shfl_xor(s, off, 64);
    if (l == 0) partials[bid * 4 + w] = s;
}

// ---------------- final: sum n partials, scale ----------------
__global__ __launch_bounds__(256) void chamfer_final(
    const float* __restrict__ partials, int n, float scale,
    float* __restrict__ out)
{
    __shared__ float ws[4];
    const int t = threadIdx.x;
    float v = 0.0f;
    for (int i = t; i < n; i += 256) v += partials[i];
#pragma unroll
    for (int off = 1; off < 64; off <<= 1) v += __shfl_xor(v, off, 64);
    if ((t & 63) == 0) ws[t >> 6] = v;
    __syncthreads();
    if (t == 0)
        out[0] = (ws[0] + ws[1] + ws[2] + ws[3]) * scale;
}

// ---------------- fallback (proven R5 vector path) ----------------
#define CPAIRS 1024
#define PA 16
#define RSTRIDE 68

__device__ __forceinline__ f32x2 pk_fma_lo(f32x2 c, f32x2 q, f32x2 acc) {
    f32x2 d;
    asm("v_pk_fma_f32 %0, %1, %2, %3 op_sel:[0,0,0] op_sel_hi:[0,1,1]"
        : "=v"(d) : "v"(c), "v"(q), "v"(acc));
    return d;
}
__device__ __forceinline__ f32x2 pk_fma_hi(f32x2 c, f32x2 q, f32x2 acc) {
    f32x2 d;
    asm("v_pk_fma_f32 %0, %1, %2, %3 op_sel:[1,0,0] op_sel_hi:[1,1,1]"
        : "=v"(d) : "v"(c), "v"(q), "v"(acc));
    return d;
}
__device__ __forceinline__ void vmin3(float& acc, float a, float b) {
    asm("v_min3_f32 %0, %1, %2, %3" : "=v"(acc) : "v"(acc), "v"(a), "v"(b));
}

__global__ __launch_bounds__(256, 4) void chamfer_vec(
    const float* __restrict__ pcs1, const float* __restrict__ pcs2,
    float* __restrict__ partials)
{
    __shared__ float4 lds[2 * CPAIRS];
    float4* bx = lds;
    float4* bz = lds + CPAIRS;

    const int bid = blockIdx.x;
    const int dir = bid >> 9;
    const int b   = (bid >> 6) & 7;
    const int ach = bid & 63;

    const float* A  = dir ? pcs2 : pcs1;
    const float* Bp = dir ? pcs1 : pcs2;
    const float* abase = A  + (size_t)b * NPTS * 3;
    const float* bbase = Bp + (size_t)b * NPTS * 3;

    const int tid = threadIdx.x;
    const int w   = tid >> 6;
    const int l   = tid & 63;

    const int apt = ach * 64 + w * PA;
    f32x2 cx[PA / 2], cy[PA / 2], cz2[PA / 2];
    float tmin[PA];
#pragma unroll
    for (int p2 = 0; p2 < PA / 2; ++p2) {
        const float* s = abase + (size_t)(apt + 2 * p2) * 3;
        cx[p2]  = (f32x2){-2.0f * s[0], -2.0f * s[3]};
        cy[p2]  = (f32x2){-2.0f * s[1], -2.0f * s[4]};
        cz2[p2] = (f32x2){-2.0f * s[2], -2.0f * s[5]};
        tmin[2 * p2] = 3.4e38f; tmin[2 * p2 + 1] = 3.4e38f;
    }

    for (int c = 0; c < 2; ++c) {
        if (c) __syncthreads();
#pragma unroll
        for (int i = 0; i < CPAIRS / 256; ++i) {
            int j  = i * 256 + tid;
            const float* s = bbase + (size_t)(c * CPAIRS + j) * 6;
            float x0 = s[0], y0 = s[1], z0 = s[2];
            float x1 = s[3], y1 = s[4], z1 = s[5];
            bx[j] = make_float4(x0, x1, y0, y1);
            bz[j] = make_float4(z0, z1,
                                fmaf(x0, x0, fmaf(y0, y0, z0 * z0)),
                                fmaf(x1, x1, fmaf(y1, y1, z1 * z1)));
        }
        __syncthreads();
#pragma unroll 4
        for (int t = 0; t < CPAIRS / 64; ++t) {
            float4 X = bx[t * 64 + l];
            float4 Z = bz[t * 64 + l];
            f32x2 qx = (f32x2){X.x, X.y};
            f32x2 qy = (f32x2){X.z, X.w};
            f32x2 qz = (f32x2){Z.x, Z.y};
            f32x2 qw = (f32x2){Z.z, Z.w};
#pragma unroll
            for (int p2 = 0; p2 < PA / 2; ++p2) {
                f32x2 d0 = pk_fma_lo(cz2[p2], qz, qw);
                d0 = pk_fma_lo(cy[p2], qy, d0);
                d0 = pk_fma_lo(cx[p2], qx, d0);
                vmin3(tmin[2 * p2], d0.x, d0.y);
                f32x2 d1 = pk_fma_hi(cz2[p2], qz, qw);
                d1 = pk_fma_hi(cy[p2], qy, d1);
                d1 = pk_fma_hi(cx[p2], qx, d1);
                vmin3(tmin[2 * p2 + 1], d1.x, d1.y);
            }
        }
    }

    __syncthreads();
    float* lds2 = (float*)lds;
#pragma unroll
    for (int p = 0; p < PA; ++p)
        lds2[(w * PA + p) * RSTRIDE + l] = tmin[p];
    __syncthreads();

    if (tid < 64) {
        const int g = tid;
        float m = 3.4e38f;
        const float4* row = (const float4*)&lds2[g * RSTRIDE];
#pragma unroll
        for (int i = 0; i < 16; ++i) {
            float4 v = row[i];
            m = fminf(fminf(m, fminf(v.x, v.y)), fminf(v.z, v.w));
        }
        const int ap = ach * 64 + g;
        float x = abase[ap * 3 + 0], y = abase[ap * 3 + 1], z = abase[ap * 3 + 2];
        float s = sqrtf(fmaxf(fmaf(x, x, fmaf(y, y, z * z)) + m, 0.0f));
#pragma unroll
        for (int off = 1; off < 64; off <<= 1) s += __shfl_xor(s, off, 64);
        if (g == 0) partials[bid] = s;
    }
}

extern "C" void kernel_launch(void* const* d_in, const int* in_sizes, int n_in,
                              void* d_out, int out_size, void* d_ws, size_t ws_size,
                              hipStream_t stream) {
    const float* pcs1 = (const float*)d_in[0];
    const float* pcs2 = (const float*)d_in[1];
    float* out = (float*)d_out;

    const size_t MB = 1048576;
    const size_t need = 4 * MB + 256 * 1024 + 8192 + 256;

    if (ws_size >= need) {
        char* w = (char*)d_ws;
        uint4* fa1 = (uint4*)(w + 0 * MB);
        uint4* fa2 = (uint4*)(w + 1 * MB);
        uint4* fb1 = (uint4*)(w + 2 * MB);
        uint4* fb2 = (uint4*)(w + 3 * MB);
        float* sqarr    = (float*)(w + 4 * MB);
        float* partials = (float*)(w + 4 * MB + 256 * 1024);

        chamfer_prep <<<dim3(256), dim3(256), 0, stream>>>(
            pcs1, pcs2, fa1, fa2, fb1, fb2, sqarr);
        chamfer_mfma <<<dim3(512), dim3(256), 0, stream>>>(
            fa1, fa2, fb1, fb2, sqarr, partials);
        chamfer_final<<<dim3(1), dim3(256), 0, stream>>>(
            partials, 2048, 1.0f / 65536.0f, out);
    } else {
        float* partials = (float*)d_ws;
        chamfer_vec  <<<dim3(1024), dim3(256), 0, stream>>>(pcs1, pcs2, partials);
        chamfer_final<<<dim3(1),    dim3(256), 0, stream>>>(
            partials, 1024, 1.0f / 65536.0f, out);
    }
}

// Round 8
// 23.018 us; speedup vs baseline: 2.1898x; 1.1043x over previous
//
#include <hip/hip_runtime.h>
#include <math.h>

// Chamfer distance, B=8, N=M=4096, D=3, fp32.
// R8: split-bf16 MFMA, occupancy-fixed. One v_mfma_f32_32x32x16_bf16 per
// 32x32 tile computes D[r][c] = sqA_r + sqB_c - 2 a_r.b_c via K-packing:
//   slots 0-2  A:hi(-2a)      B:hi(b)
//   slots 3-5  A:hi(-2a)      B:lo(b)
//   slots 6-8  A:lo(-2a)      B:hi(b)
//   slots 9-11 A:lo(-2a)      B:lo(b)
//   slot 12,13 A:sqA_hi,lo    B:1,1
//   slot 14,15 A:1,1          B:sqB_hi,lo     <- new in R8 (was zeros)
// Each block sweeps HALF the r-tiles (64) -> 1024 blocks = 4 blocks/CU =
// 4 waves/SIMD (R7 had 2). The two half-blocks combine their per-col mins
// with atomicMin on uint-mapped clamped floats (deterministic, exact).
// MFMA floor: 262144 mfma * 65536 flop / 2.5 PF ~ 6.8 us.

typedef __attribute__((ext_vector_type(8)))  short bf16x8;
typedef __attribute__((ext_vector_type(16))) float f32x16;
typedef float f32x2 __attribute__((ext_vector_type(2)));

#define NPTS 4096
#define BATCH 8
#define FRAG_PER_B 8192u   // per batch-cloud: 128 tiles * 2 halves * 32 rows

union FragCast { uint4 u; bf16x8 v; };

__device__ __forceinline__ unsigned short f2bf(float f) {
    unsigned u = __float_as_uint(f);
    return (unsigned short)((u + 0x7FFFu + ((u >> 16) & 1u)) >> 16);
}
__device__ __forceinline__ float bf2f(unsigned short h) {
    return __uint_as_float(((unsigned)h) << 16);
}
__device__ __forceinline__ unsigned pk(unsigned short a, unsigned short b) {
    return (unsigned)a | ((unsigned)b << 16);
}

// ---------------- prep: fragments + dist init ----------------
__global__ __launch_bounds__(256) void chamfer_prep(
    const float* __restrict__ pcs1, const float* __restrict__ pcs2,
    uint4* __restrict__ fa1, uint4* __restrict__ fa2,
    uint4* __restrict__ fb1, uint4* __restrict__ fb2,
    unsigned* __restrict__ dist)
{
    const int gid   = blockIdx.x * 256 + threadIdx.x;  // [0, 65536)
    const int cloud = gid >> 15;
    const int idx   = gid & 32767;
    const int b     = idx >> 12;
    const int pt    = idx & 4095;

    dist[gid] = 0x7F800000u;   // +inf; layout == ((cloud*8+b)*4096 + pt)

    const float* src = (cloud ? pcs2 : pcs1) + ((size_t)b * NPTS + pt) * 3;
    float x = src[0], y = src[1], z = src[2];
    float sq = fmaf(x, x, fmaf(y, y, z * z));

    // A-role: hi/lo split of -2*coord, plus split of |a|^2
    float m2x = -2.0f * x, m2y = -2.0f * y, m2z = -2.0f * z;
    unsigned short hx = f2bf(m2x), hy = f2bf(m2y), hz = f2bf(m2z);
    unsigned short lx = f2bf(m2x - bf2f(hx));
    unsigned short ly = f2bf(m2y - bf2f(hy));
    unsigned short lz = f2bf(m2z - bf2f(hz));
    unsigned short sh = f2bf(sq);
    unsigned short sl = f2bf(sq - bf2f(sh));

    // B-role: hi/lo split of raw coord, plus split of |b|^2
    unsigned short px = f2bf(x), py = f2bf(y), pz = f2bf(z);
    unsigned short qx = f2bf(x - bf2f(px));
    unsigned short qy = f2bf(y - bf2f(py));
    unsigned short qz = f2bf(z - bf2f(pz));
    const unsigned short ONE = 0x3F80;

    uint4 a0 = make_uint4(pk(hx, hy), pk(hz, hx), pk(hy, hz), pk(lx, ly));
    uint4 a1 = make_uint4(pk(lz, lx), pk(ly, lz), pk(sh, sl), pk(ONE, ONE));
    uint4 b0 = make_uint4(pk(px, py), pk(pz, qx), pk(qy, qz), pk(px, py));
    uint4 b1 = make_uint4(pk(pz, qx), pk(qy, qz), pk(ONE, ONE), pk(sh, sl));

    const int tile = pt >> 5, row = pt & 31;
    const size_t i0 = (size_t)b * FRAG_PER_B + ((size_t)tile * 2 + 0) * 32 + row;
    const size_t i1 = (size_t)b * FRAG_PER_B + ((size_t)tile * 2 + 1) * 32 + row;
    uint4* fa = cloud ? fa2 : fa1;
    uint4* fb = cloud ? fb2 : fb1;
    fa[i0] = a0; fa[i1] = a1;
    fb[i0] = b0; fb[i1] = b1;
}

// ---------------- main: 1024 blocks x 256 threads (4 waves) ----------------
// bid: dir = bid>>9, b = (bid>>6)&7, mch = (bid>>1)&31, half = bid&1.
// wave w owns m-tile mch*4+w (32 cols); sweeps 64 r-tiles (its half),
// A-frags LDS-staged in 2 phases of 32 tiles (32 KB -> 4 blocks/CU).
__global__ __launch_bounds__(256, 4) void chamfer_mfma(
    const uint4* __restrict__ fa1, const uint4* __restrict__ fa2,
    const uint4* __restrict__ fb1, const uint4* __restrict__ fb2,
    unsigned* __restrict__ dist)
{
    __shared__ uint4 stage[2048];   // 32 tiles * 2 halves * 32 rows

    const int bid  = blockIdx.x;
    const int dir  = bid >> 9;
    const int b    = (bid >> 6) & 7;
    const int mch  = (bid >> 1) & 31;
    const int half = bid & 1;

    const uint4* fA = (dir ? fa1 : fa2) + (size_t)b * FRAG_PER_B
                      + (size_t)half * 4096;             // 64 r-tiles
    const uint4* fB = (dir ? fb2 : fb1) + (size_t)b * FRAG_PER_B;

    const int tid = threadIdx.x;
    const int w   = tid >> 6;
    const int l   = tid & 63;
    const int hf  = l >> 5;
    const int ln  = l & 31;
    const int mtile = mch * 4 + w;

    FragCast bq;
    bq.u = fB[((size_t)mtile * 2 + hf) * 32 + ln];

    const f32x16 cz = {0.f,0.f,0.f,0.f,0.f,0.f,0.f,0.f,
                       0.f,0.f,0.f,0.f,0.f,0.f,0.f,0.f};
    float acc0 = 3.4e38f, acc1 = 3.4e38f;

    for (int phase = 0; phase < 2; ++phase) {
        __syncthreads();                      // prev phase's reads done
#pragma unroll
        for (int i = 0; i < 8; ++i)
            stage[i * 256 + tid] = fA[(size_t)phase * 2048 + i * 256 + tid];
        __syncthreads();

#pragma unroll 2
        for (int j2 = 0; j2 < 16; ++j2) {
            FragCast aq0, aq1;
            aq0.u = stage[(j2 * 4 + 0 + hf) * 32 + ln];
            aq1.u = stage[(j2 * 4 + 2 + hf) * 32 + ln];
            f32x16 D0 = __builtin_amdgcn_mfma_f32_32x32x16_bf16(
                aq0.v, bq.v, cz, 0, 0, 0);
            f32x16 D1 = __builtin_amdgcn_mfma_f32_32x32x16_bf16(
                aq1.v, bq.v, cz, 0, 0, 0);
#pragma unroll
            for (int i = 0; i < 8; ++i)       // -> v_min3_f32 each
                acc0 = fminf(fminf(acc0, D0[2 * i]), D0[2 * i + 1]);
#pragma unroll
            for (int i = 0; i < 8; ++i)
                acc1 = fminf(fminf(acc1, D1[2 * i]), D1[2 * i + 1]);
        }
    }

    // lanes l and l+32 hold complementary row halves of the same col
    float accmin = fminf(acc0, acc1);
    accmin = fminf(accmin, __shfl_xor(accmin, 32, 64));

    if (l < 32) {
        const int col = mtile * 32 + ln;
        float d = fmaxf(accmin, 0.0f);        // clamp cancellation
        // nonneg floats: uint bit pattern is monotone -> exact atomic min
        atomicMin(&dist[(((unsigned)dir * 8 + b) << 12) + col],
                  __float_as_uint(d));
    }
}

// ---------------- reduce 1: 65536 dists -> 64 partial sums ----------------
__global__ __launch_bounds__(256) void chamfer_red1(
    const unsigned* __restrict__ dist, float* __restrict__ bpart)
{
    __shared__ float ws[4];
    const int t = threadIdx.x;
    const uint4* d4 = (const uint4*)dist;     // 4 entries per thread
    uint4 v = d4[blockIdx.x * 256 + t];
    float s = sqrtf(__uint_as_float(v.x)) + sqrtf(__uint_as_float(v.y))
            + sqrtf(__uint_as_float(v.z)) + sqrtf(__uint_as_float(v.w));
#pragma unroll
    for (int off = 1; off < 64; off <<= 1) s += __shfl_xor(s, off, 64);
    if ((t & 63) == 0) ws[t >> 6] = s;
    __syncthreads();
    if (t == 0)
        bpart[blockIdx.x] = ws[0] + ws[1] + ws[2] + ws[3];
}

// ---------------- reduce 2: 64 -> scalar ----------------
__global__ __launch_bounds__(64) void chamfer_red2(
    const float* __restrict__ bpart, float* __restrict__ out)
{
    float v = bpart[threadIdx.x];
#pragma unroll
    for (int off = 1; off < 64; off <<= 1) v += __shfl_xor(v, off, 64);
    if (threadIdx.x == 0) out[0] = v * (1.0f / 65536.0f);
    // loss = 0.5*(sum1/32768 + sum2/32768) = (sum1+sum2)/65536
}

// ---------------- fallback (proven R5 vector path) ----------------
#define CPAIRS 1024
#define PA 16
#define RSTRIDE 68

__device__ __forceinline__ f32x2 pk_fma_lo(f32x2 c, f32x2 q, f32x2 acc) {
    f32x2 d;
    asm("v_pk_fma_f32 %0, %1, %2, %3 op_sel:[0,0,0] op_sel_hi:[0,1,1]"
        : "=v"(d) : "v"(c), "v"(q), "v"(acc));
    return d;
}
__device__ __forceinline__ f32x2 pk_fma_hi(f32x2 c, f32x2 q, f32x2 acc) {
    f32x2 d;
    asm("v_pk_fma_f32 %0, %1, %2, %3 op_sel:[1,0,0] op_sel_hi:[1,1,1]"
        : "=v"(d) : "v"(c), "v"(q), "v"(acc));
    return d;
}
__device__ __forceinline__ void vmin3(float& acc, float a, float b) {
    asm("v_min3_f32 %0, %1, %2, %3" : "=v"(acc) : "v"(acc), "v"(a), "v"(b));
}

__global__ __launch_bounds__(256, 4) void chamfer_vec(
    const float* __restrict__ pcs1, const float* __restrict__ pcs2,
    float* __restrict__ partials)
{
    __shared__ float4 lds[2 * CPAIRS];
    float4* bx = lds;
    float4* bz = lds + CPAIRS;

    const int bid = blockIdx.x;
    const int dir = bid >> 9;
    const int b   = (bid >> 6) & 7;
    const int ach = bid & 63;

    const float* A  = dir ? pcs2 : pcs1;
    const float* Bp = dir ? pcs1 : pcs2;
    const float* abase = A  + (size_t)b * NPTS * 3;
    const float* bbase = Bp + (size_t)b * NPTS * 3;

    const int tid = threadIdx.x;
    const int w   = tid >> 6;
    const int l   = tid & 63;

    const int apt = ach * 64 + w * PA;
    f32x2 cx[PA / 2], cy[PA / 2], cz2[PA / 2];
    float tmin[PA];
#pragma unroll
    for (int p2 = 0; p2 < PA / 2; ++p2) {
        const float* s = abase + (size_t)(apt + 2 * p2) * 3;
        cx[p2]  = (f32x2){-2.0f * s[0], -2.0f * s[3]};
        cy[p2]  = (f32x2){-2.0f * s[1], -2.0f * s[4]};
        cz2[p2] = (f32x2){-2.0f * s[2], -2.0f * s[5]};
        tmin[2 * p2] = 3.4e38f; tmin[2 * p2 + 1] = 3.4e38f;
    }

    for (int c = 0; c < 2; ++c) {
        if (c) __syncthreads();
#pragma unroll
        for (int i = 0; i < CPAIRS / 256; ++i) {
            int j  = i * 256 + tid;
            const float* s = bbase + (size_t)(c * CPAIRS + j) * 6;
            float x0 = s[0], y0 = s[1], z0 = s[2];
            float x1 = s[3], y1 = s[4], z1 = s[5];
            bx[j] = make_float4(x0, x1, y0, y1);
            bz[j] = make_float4(z0, z1,
                                fmaf(x0, x0, fmaf(y0, y0, z0 * z0)),
                                fmaf(x1, x1, fmaf(y1, y1, z1 * z1)));
        }
        __syncthreads();
#pragma unroll 4
        for (int t = 0; t < CPAIRS / 64; ++t) {
            float4 X = bx[t * 64 + l];
            float4 Z = bz[t * 64 + l];
            f32x2 qx = (f32x2){X.x, X.y};
            f32x2 qy = (f32x2){X.z, X.w};
            f32x2 qz = (f32x2){Z.x, Z.y};
            f32x2 qw = (f32x2){Z.z, Z.w};
#pragma unroll
            for (int p2 = 0; p2 < PA / 2; ++p2) {
                f32x2 d0 = pk_fma_lo(cz2[p2], qz, qw);
                d0 = pk_fma_lo(cy[p2], qy, d0);
                d0 = pk_fma_lo(cx[p2], qx, d0);
                vmin3(tmin[2 * p2], d0.x, d0.y);
                f32x2 d1 = pk_fma_hi(cz2[p2], qz, qw);
                d1 = pk_fma_hi(cy[p2], qy, d1);
                d1 = pk_fma_hi(cx[p2], qx, d1);
                vmin3(tmin[2 * p2 + 1], d1.x, d1.y);
            }
        }
    }

    __syncthreads();
    float* lds2 = (float*)lds;
#pragma unroll
    for (int p = 0; p < PA; ++p)
        lds2[(w * PA + p) * RSTRIDE + l] = tmin[p];
    __syncthreads();

    if (tid < 64) {
        const int g = tid;
        float m = 3.4e38f;
        const float4* row = (const float4*)&lds2[g * RSTRIDE];
#pragma unroll
        for (int i = 0; i < 16; ++i) {
            float4 v = row[i];
            m = fminf(fminf(m, fminf(v.x, v.y)), fminf(v.z, v.w));
        }
        const int ap = ach * 64 + g;
        float x = abase[ap * 3 + 0], y = abase[ap * 3 + 1], z = abase[ap * 3 + 2];
        float s = sqrtf(fmaxf(fmaf(x, x, fmaf(y, y, z * z)) + m, 0.0f));
#pragma unroll
        for (int off = 1; off < 64; off <<= 1) s += __shfl_xor(s, off, 64);
        if (g == 0) partials[bid] = s;
    }
}

__global__ __launch_bounds__(256) void chamfer_final(
    const float* __restrict__ partials, int n, float scale,
    float* __restrict__ out)
{
    __shared__ float ws[4];
    const int t = threadIdx.x;
    float v = 0.0f;
    for (int i = t; i < n; i += 256) v += partials[i];
#pragma unroll
    for (int off = 1; off < 64; off <<= 1) v += __shfl_xor(v, off, 64);
    if ((t & 63) == 0) ws[t >> 6] = v;
    __syncthreads();
    if (t == 0)
        out[0] = (ws[0] + ws[1] + ws[2] + ws[3]) * scale;
}

extern "C" void kernel_launch(void* const* d_in, const int* in_sizes, int n_in,
                              void* d_out, int out_size, void* d_ws, size_t ws_size,
                              hipStream_t stream) {
    const float* pcs1 = (const float*)d_in[0];
    const float* pcs2 = (const float*)d_in[1];
    float* out = (float*)d_out;

    const size_t MB = 1048576;
    const size_t need = 4 * MB + 256 * 1024 + 1024;

    if (ws_size >= need) {
        char* w = (char*)d_ws;
        uint4* fa1 = (uint4*)(w + 0 * MB);
        uint4* fa2 = (uint4*)(w + 1 * MB);
        uint4* fb1 = (uint4*)(w + 2 * MB);
        uint4* fb2 = (uint4*)(w + 3 * MB);
        unsigned* dist = (unsigned*)(w + 4 * MB);           // 65536 u32
        float* bpart   = (float*)(w + 4 * MB + 256 * 1024); // 64 f32

        chamfer_prep<<<dim3(256),  dim3(256), 0, stream>>>(
            pcs1, pcs2, fa1, fa2, fb1, fb2, dist);
        chamfer_mfma<<<dim3(1024), dim3(256), 0, stream>>>(
            fa1, fa2, fb1, fb2, dist);
        chamfer_red1<<<dim3(64),   dim3(256), 0, stream>>>(dist, bpart);
        chamfer_red2<<<dim3(1),    dim3(64),  0, stream>>>(bpart, out);
    } else {
        float* partials = (float*)d_ws;
        chamfer_vec  <<<dim3(1024), dim3(256), 0, stream>>>(pcs1, pcs2, partials);
        chamfer_final<<<dim3(1),    dim3(256), 0, stream>>>(
            partials, 1024, 1.0f / 65536.0f, out);
    }
}